// Round 6
// baseline (1107.209 us; speedup 1.0000x reference)
//
#include <hip/hip_runtime.h>
#include <hip/hip_bf16.h>
#include <math.h>

#define BB 32
#define CC 64
#define C2 32
#define HH 32
#define WW 32
#define HW 1024
#define NTOT 3278
#define NPAD2 3328   // padded N (multiple of 128) for MFMA corr + fold
#define NT26 26      // NPAD2 / 128
#define KC 288       // correlation K = C2*9

typedef __bf16 bf16x8 __attribute__((ext_vector_type(8)));
typedef float  f32x4  __attribute__((ext_vector_type(4)));

__device__ __constant__ int SC_SIZE[5] = {32, 28, 25, 22, 19};
__device__ __constant__ int SC_OFF[6]  = {0, 1024, 1808, 2433, 2917, 3278};

// ---------------- fused feature kernel: all convs on the full 32x32 grid ----------------
// og 0..1: mb 16-ch halves (w_base); og 2..3: rm_full halves (w_match); og 4..7: base 16-ch quarters (w_asm)
__global__ void k_feats(const float* __restrict__ x,
                        const float* __restrict__ wb, const float* __restrict__ bb, const float* __restrict__ ab,
                        const float* __restrict__ wm, const float* __restrict__ bm, const float* __restrict__ am,
                        const float* __restrict__ wa, const float* __restrict__ ba, const float* __restrict__ aa,
                        float* __restrict__ mb, float* __restrict__ rmf, __bf16* __restrict__ basef) {
    int og = blockIdx.y;
    __shared__ float wsm[16 * CC];
    __shared__ float bsh[16];
    __shared__ float ash;
    int tid = threadIdx.x;
    {
        const float* wsrc; const float* bsrc; const float* asrc; int o0;
        if (og < 2)      { wsrc = wb; bsrc = bb; asrc = ab; o0 = og * 16; }
        else if (og < 4) { wsrc = wm; bsrc = bm; asrc = am; o0 = (og - 2) * 16; }
        else             { wsrc = wa; bsrc = ba; asrc = aa; o0 = (og - 4) * 16; }
        for (int i = tid; i < 16 * CC; i += 256) wsm[i] = wsrc[o0 * CC + i];
        if (tid < 16) bsh[tid] = bsrc[o0 + tid];
        if (tid == 16) ash = asrc[0];
    }
    __syncthreads();
    int t = blockIdx.x * 256 + tid;
    int b = t >> 10, p = t & 1023;
    float xv[CC];
    const float* xb = x + (size_t)b * CC * HW + p;
#pragma unroll
    for (int c = 0; c < CC; ++c) xv[c] = xb[c * HW];
    float alpha = ash;
    if (og < 2) {
        int o0 = og * 16;
#pragma unroll
        for (int oi = 0; oi < 16; ++oi) {
            float acc = bsh[oi];
#pragma unroll
            for (int c = 0; c < CC; ++c) acc += wsm[oi * CC + c] * xv[c];
            mb[((size_t)b * C2 + o0 + oi) * HW + p] = acc >= 0.f ? acc : alpha * acc;
        }
    } else if (og < 4) {
        int o0 = (og - 2) * 16;
#pragma unroll
        for (int oi = 0; oi < 16; ++oi) {
            float acc = bsh[oi];
#pragma unroll
            for (int c = 0; c < CC; ++c) acc += wsm[oi * CC + c] * xv[c];
            rmf[((size_t)b * C2 + o0 + oi) * HW + p] = acc >= 0.f ? acc : alpha * acc;
        }
    } else {
        int o0 = (og - 4) * 16;
#pragma unroll
        for (int oi = 0; oi < 16; ++oi) {
            float acc = bsh[oi];
#pragma unroll
            for (int c = 0; c < CC; ++c) acc += wsm[oi * CC + c] * xv[c];
            basef[((size_t)b * CC + o0 + oi) * HW + p] = (__bf16)(acc >= 0.f ? acc : alpha * acc);
        }
    }
}

// ---------------- per-pixel sum-of-squares of mb and rmf ----------------
__global__ void k_ss(const float* __restrict__ mb, const float* __restrict__ rmf,
                     float* __restrict__ mbss, float* __restrict__ rmss) {
    int t = blockIdx.x * 256 + threadIdx.x;   // [0, BB*HW)
    int b = t >> 10, p = t & 1023;
    const float* m = mb + (size_t)b * C2 * HW + p;
    const float* r = rmf + (size_t)b * C2 * HW + p;
    float sb = 0.f, sm = 0.f;
#pragma unroll
    for (int c = 0; c < C2; ++c) {
        float v1 = m[c * HW]; sb += v1 * v1;
        float v2 = r[c * HW]; sm += v2 * v2;
    }
    mbss[t] = sb;
    rmss[t] = sm;
}

// ---------------- neighbor table: full-grid position of tap kk at concat-index n, or -1 ----------------
__global__ void k_nbr(int* __restrict__ nbr_pos) {
    int n = blockIdx.x * blockDim.x + threadIdx.x;
    if (n >= NTOT) return;
    int s = 0;
    while (s < 4 && n >= SC_OFF[s + 1]) ++s;
    int q = n - SC_OFF[s];
    int hs = SC_SIZE[s];
    int ny = q / hs, nx = q % hs;
    for (int dy = 0; dy < 3; ++dy)
        for (int dx = 0; dx < 3; ++dx) {
            int yy = ny + dy - 1, xx = nx + dx - 1;
            int pos = -1;
            if (yy >= 0 && yy < hs && xx >= 0 && xx < hs)
                pos = ((yy * HH) / hs) * WW + (xx * WW) / hs;
            nbr_pos[(dy * 3 + dx) * NTOT + n] = pos;
        }
}

// ---------------- per-(b,p) logit upper bound: Mub = 10*||xp[p]|| from mbss 9-tap ----------------
__global__ void k_qnorm(const float* __restrict__ mbss, float* __restrict__ qub) {
    int t = blockIdx.x * blockDim.x + threadIdx.x;   // [0, BB*HW)
    int b = t >> 10, p = t & 1023;
    int y = p >> 5, x = p & 31;
    float s = 0.f;
#pragma unroll
    for (int dy = 0; dy < 3; ++dy)
#pragma unroll
        for (int dx = 0; dx < 3; ++dx) {
            int yy = y + dy - 1, xx = x + dx - 1;
            if (yy >= 0 && yy < HH && xx >= 0 && xx < WW)
                s += mbss[(size_t)b * HW + yy * WW + xx];
        }
    qub[t] = 10.0f * sqrtf(s);
}

// ---------------- per-(b,n) filter norms from rmss 9-tap; sinv = 10/max(norm,1e-4) ----------------
__global__ void k_norms(const float* __restrict__ rmss, const int* __restrict__ nbr_pos,
                        float* __restrict__ sinv) {
    int t = blockIdx.x * blockDim.x + threadIdx.x;
    if (t >= BB * NTOT) return;
    int b = t / NTOT, n = t % NTOT;
    float sum = 0.f;
#pragma unroll
    for (int kk = 0; kk < 9; ++kk) {
        int pos = nbr_pos[kk * NTOT + n];
        if (pos >= 0) sum += rmss[(size_t)b * HW + pos];
    }
    sinv[t] = 10.0f / fmaxf(sqrtf(sum), 1e-4f);
}

// ---------------- xpat gather: mb patches -> [cb][p][KC] bf16 hi/lo ----------------
__global__ void k_xpat(const float* __restrict__ mb, __bf16* __restrict__ xh,
                       __bf16* __restrict__ xl, int b0) {
    int t = blockIdx.x * 256 + threadIdx.x;   // over HW*KC
    int cb = blockIdx.y;
    int p = t / KC, k = t % KC;
    int c2 = k / 9, kk = k % 9;
    int py = (p >> 5) + kk / 3 - 1;
    int px = (p & 31) + kk % 3 - 1;
    float v = 0.f;
    if (py >= 0 && py < HH && px >= 0 && px < WW)
        v = mb[((size_t)(b0 + cb) * C2 + c2) * HW + py * WW + px];
    __bf16 hi = (__bf16)v;
    size_t o = ((size_t)cb * HW + p) * KC + k;
    xh[o] = hi;
    xl[o] = (__bf16)(v - (float)hi);
}

// ---------------- wib gather: wi rows from rm_full -> [cb][n][KC] bf16 hi/lo ----------------
__global__ void k_wib(const float* __restrict__ rmf, const int* __restrict__ nbr_pos,
                      __bf16* __restrict__ wh, __bf16* __restrict__ wl, int b0) {
    int t = blockIdx.x * 256 + threadIdx.x;   // over NPAD2*KC
    int cb = blockIdx.y;
    int n = t / KC, k = t % KC;
    int c2 = k / 9, kk = k % 9;
    float v = 0.f;
    if (n < NTOT) {
        int pos = nbr_pos[kk * NTOT + n];
        if (pos >= 0) v = rmf[((size_t)(b0 + cb) * C2 + c2) * HW + pos];
    }
    __bf16 hi = (__bf16)v;
    size_t o = ((size_t)cb * NPAD2 + n) * KC + k;
    wh[o] = hi;
    wl[o] = (__bf16)(v - (float)hi);
}

// ---------------- correlation GEMM (MFMA, split-bf16) + t = exp(v - Mub[p]) epilogue ----------------
__global__ void k_corr_mfma(const __bf16* __restrict__ xh, const __bf16* __restrict__ xl,
                            const __bf16* __restrict__ wh, const __bf16* __restrict__ wl,
                            const float* __restrict__ sinv, const float* __restrict__ qub,
                            __bf16* __restrict__ tbuf, float* __restrict__ partS, int b0) {
    int ptile = blockIdx.x;   // 16 tiles of 64 p
    int ntile = blockIdx.y;   // 26 tiles of 128 n
    int cb    = blockIdx.z;
    int tid  = threadIdx.x;
    int lane = tid & 63, wave = tid >> 6;
    int row16 = lane & 15, quad = lane >> 4;

    __shared__ __bf16 Ah[64 * 40], Al[64 * 40];
    __shared__ __bf16 Bh[128 * 40], Bl[128 * 40];
    __shared__ float sMub[64];
    __shared__ float redS[4][64];

    if (tid < 64) sMub[tid] = qub[(size_t)(b0 + cb) * HW + ptile * 64 + tid];

    const __bf16* Aph = xh + ((size_t)cb * HW + ptile * 64) * KC;
    const __bf16* Apl = xl + ((size_t)cb * HW + ptile * 64) * KC;
    const __bf16* Bph = wh + ((size_t)cb * NPAD2 + ntile * 128) * KC;
    const __bf16* Bpl = wl + ((size_t)cb * NPAD2 + ntile * 128) * KC;

    f32x4 acc[4][2];
#pragma unroll
    for (int i = 0; i < 4; ++i)
#pragma unroll
        for (int j = 0; j < 2; ++j) acc[i][j] = (f32x4){0.f, 0.f, 0.f, 0.f};

    int lr = tid >> 2, lk = (tid & 3) * 8;
    for (int k0 = 0; k0 < KC; k0 += 32) {
        *(bf16x8*)&Ah[lr * 40 + lk] = *(const bf16x8*)(Aph + (size_t)lr * KC + k0 + lk);
        *(bf16x8*)&Al[lr * 40 + lk] = *(const bf16x8*)(Apl + (size_t)lr * KC + k0 + lk);
#pragma unroll
        for (int i = 0; i < 2; ++i) {
            int r = tid + i * 256;
            int rr = r >> 2, rk = (r & 3) * 8;
            *(bf16x8*)&Bh[rr * 40 + rk] = *(const bf16x8*)(Bph + (size_t)rr * KC + k0 + rk);
            *(bf16x8*)&Bl[rr * 40 + rk] = *(const bf16x8*)(Bpl + (size_t)rr * KC + k0 + rk);
        }
        __syncthreads();
        bf16x8 ah[4], al[4], bh[2], bl[2];
#pragma unroll
        for (int m = 0; m < 4; ++m) {
            ah[m] = *(const bf16x8*)&Ah[(m * 16 + row16) * 40 + quad * 8];
            al[m] = *(const bf16x8*)&Al[(m * 16 + row16) * 40 + quad * 8];
        }
#pragma unroll
        for (int nb = 0; nb < 2; ++nb) {
            bh[nb] = *(const bf16x8*)&Bh[(wave * 32 + nb * 16 + row16) * 40 + quad * 8];
            bl[nb] = *(const bf16x8*)&Bl[(wave * 32 + nb * 16 + row16) * 40 + quad * 8];
        }
#pragma unroll
        for (int m = 0; m < 4; ++m)
#pragma unroll
            for (int nb = 0; nb < 2; ++nb) {
                acc[m][nb] = __builtin_amdgcn_mfma_f32_16x16x32_bf16(ah[m], bh[nb], acc[m][nb], 0, 0, 0);
                acc[m][nb] = __builtin_amdgcn_mfma_f32_16x16x32_bf16(ah[m], bl[nb], acc[m][nb], 0, 0, 0);
                acc[m][nb] = __builtin_amdgcn_mfma_f32_16x16x32_bf16(al[m], bh[nb], acc[m][nb], 0, 0, 0);
            }
        __syncthreads();
    }

    // ---- epilogue: v = acc*sinv[n]; t = exp(v - Mub[p]); row-partial sums ----
    int nn[2];
    float sv[2];
    bool valid[2];
#pragma unroll
    for (int nb = 0; nb < 2; ++nb) {
        nn[nb] = ntile * 128 + wave * 32 + nb * 16 + row16;
        valid[nb] = nn[nb] < NTOT;
        sv[nb] = valid[nb] ? sinv[(size_t)(b0 + cb) * NTOT + nn[nb]] : 0.f;
    }
    float sm[4][4] = {};
#pragma unroll
    for (int m = 0; m < 4; ++m)
#pragma unroll
        for (int nb = 0; nb < 2; ++nb) {
            size_t rb = ((size_t)cb * HW + ptile * 64 + m * 16) * NPAD2 + nn[nb];
#pragma unroll
            for (int r = 0; r < 4; ++r) {
                float mub = sMub[m * 16 + quad * 4 + r];
                float e = valid[nb] ? __expf(acc[m][nb][r] * sv[nb] - mub) : 0.f;
                tbuf[rb + (size_t)(quad * 4 + r) * NPAD2] = (__bf16)e;
                sm[m][r] += e;
            }
        }
#pragma unroll
    for (int msk = 1; msk < 16; msk <<= 1)
#pragma unroll
        for (int m = 0; m < 4; ++m)
#pragma unroll
            for (int r = 0; r < 4; ++r) sm[m][r] += __shfl_xor(sm[m][r], msk, 64);
    if (row16 == 0)
#pragma unroll
        for (int m = 0; m < 4; ++m)
#pragma unroll
            for (int r = 0; r < 4; ++r) redS[wave][m * 16 + quad * 4 + r] = sm[m][r];
    __syncthreads();
    if (wave == 0 && row16 == 0) {
#pragma unroll
        for (int m = 0; m < 4; ++m)
#pragma unroll
            for (int r = 0; r < 4; ++r) {
                int p = m * 16 + quad * 4 + r;
                float S = redS[0][p] + redS[1][p] + redS[2][p] + redS[3][p];
                partS[((size_t)cb * HW + ptile * 64 + p) * NT26 + ntile] = S;
            }
    }
}

// ---------------- row sum reduce: fin[row] = 1 / sum_nt partS ----------------
__global__ void k_rowsum(const float* __restrict__ partS, float* __restrict__ fin) {
    int row = blockIdx.x * 256 + threadIdx.x;   // [0, CB*HW)
    float s = 0.f;
#pragma unroll
    for (int nt = 0; nt < NT26; ++nt) s += partS[(size_t)row * NT26 + nt];
    fin[row] = 1.0f / fmaxf(s, 1e-38f);
}

// ---------------- V gather: Vb[cb][m=576][NPAD2] bf16 from base_full ----------------
__global__ void k_vgather(const __bf16* __restrict__ basef, const int* __restrict__ nbr_pos,
                          __bf16* __restrict__ Vb, int b0) {
    int n = blockIdx.x * 256 + threadIdx.x;
    int m = blockIdx.y;
    int cb = blockIdx.z;
    int c = m / 9, kk = m % 9;
    __bf16 v = (__bf16)0.f;
    if (n < NTOT) {
        int pos = nbr_pos[kk * NTOT + n];
        if (pos >= 0) v = basef[((size_t)(b0 + cb) * CC + c) * HW + pos];
    }
    Vb[((size_t)cb * 576 + m) * NPAD2 + n] = v;
}

// ---------------- fold GEMM (MFMA bf16, K-step 64, reg prefetch) ----------------
// outacc[cb][m][p] = (1/S[p]) * sum_n V[m,n]*t[p,n]
#define FSTR 72   // LDS row stride in bf16 (144 B, 16B-aligned)
__global__ void k_fold_mfma(const __bf16* __restrict__ Vb, const __bf16* __restrict__ tbuf,
                            const float* __restrict__ fin, float* __restrict__ outacc) {
    int ptile = blockIdx.x;   // 8 tiles of 128 p
    int mtile = blockIdx.y;   // 9 tiles of 64 m
    int cb    = blockIdx.z;
    int tid  = threadIdx.x;
    int lane = tid & 63, wave = tid >> 6;
    int row16 = lane & 15, quad = lane >> 4;

    __shared__ __bf16 Als[64 * FSTR];
    __shared__ __bf16 Bls[128 * FSTR];

    const __bf16* Vp = Vb   + (size_t)cb * 576 * NPAD2 + (size_t)mtile * 64 * NPAD2;
    const __bf16* Pp = tbuf + (size_t)cb * HW  * NPAD2 + (size_t)ptile * 128 * NPAD2;

    f32x4 acc[4][2];
#pragma unroll
    for (int i = 0; i < 4; ++i)
#pragma unroll
        for (int j = 0; j < 2; ++j) acc[i][j] = (f32x4){0.f, 0.f, 0.f, 0.f};

    int sr = tid >> 3, sk = (tid & 7) * 8;   // staging: 32 rows/pass, 64 k
    bf16x8 pa[2], pb[4];
#pragma unroll
    for (int i = 0; i < 2; ++i)
        pa[i] = *(const bf16x8*)(Vp + (size_t)(i * 32 + sr) * NPAD2 + sk);
#pragma unroll
    for (int i = 0; i < 4; ++i)
        pb[i] = *(const bf16x8*)(Pp + (size_t)(i * 32 + sr) * NPAD2 + sk);

    for (int k0 = 0; k0 < NPAD2; k0 += 64) {
        __syncthreads();   // previous step's LDS reads done
#pragma unroll
        for (int i = 0; i < 2; ++i)
            *(bf16x8*)&Als[(i * 32 + sr) * FSTR + sk] = pa[i];
#pragma unroll
        for (int i = 0; i < 4; ++i)
            *(bf16x8*)&Bls[(i * 32 + sr) * FSTR + sk] = pb[i];
        // prefetch next step while MFMA runs
        if (k0 + 64 < NPAD2) {
#pragma unroll
            for (int i = 0; i < 2; ++i)
                pa[i] = *(const bf16x8*)(Vp + (size_t)(i * 32 + sr) * NPAD2 + k0 + 64 + sk);
#pragma unroll
            for (int i = 0; i < 4; ++i)
                pb[i] = *(const bf16x8*)(Pp + (size_t)(i * 32 + sr) * NPAD2 + k0 + 64 + sk);
        }
        __syncthreads();   // LDS tile ready
#pragma unroll
        for (int kh = 0; kh < 2; ++kh) {
            bf16x8 af[4], bf[2];
#pragma unroll
            for (int mb = 0; mb < 4; ++mb)
                af[mb] = *(const bf16x8*)&Als[(mb * 16 + row16) * FSTR + kh * 32 + quad * 8];
#pragma unroll
            for (int pbi = 0; pbi < 2; ++pbi)
                bf[pbi] = *(const bf16x8*)&Bls[(wave * 32 + pbi * 16 + row16) * FSTR + kh * 32 + quad * 8];
#pragma unroll
            for (int mb = 0; mb < 4; ++mb)
#pragma unroll
                for (int pbi = 0; pbi < 2; ++pbi)
                    acc[mb][pbi] = __builtin_amdgcn_mfma_f32_16x16x32_bf16(af[mb], bf[pbi], acc[mb][pbi], 0, 0, 0);
        }
    }
    float fsc[2];
#pragma unroll
    for (int pbi = 0; pbi < 2; ++pbi)
        fsc[pbi] = fin[(size_t)cb * HW + ptile * 128 + wave * 32 + pbi * 16 + row16];
#pragma unroll
    for (int mb = 0; mb < 4; ++mb)
#pragma unroll
        for (int pbi = 0; pbi < 2; ++pbi) {
#pragma unroll
            for (int r = 0; r < 4; ++r) {
                int mg = mtile * 64 + mb * 16 + quad * 4 + r;
                int pg = ptile * 128 + wave * 32 + pbi * 16 + row16;
                outacc[((size_t)cb * 576 + mg) * HW + pg] = acc[mb][pbi][r] * fsc[pbi];
            }
        }
}

// ---------------- epilogue ----------------
__global__ void k_epilogue(const float* __restrict__ x, const float* __restrict__ outacc,
                           float* __restrict__ out, int b0) {
    int t = blockIdx.x * blockDim.x + threadIdx.x;
    int cb = t >> 16;
    int c = (t >> 10) & 63;
    int p = t & 1023;
    int b = b0 + cb;
    int y = p >> 5, xx = p & 31;
    float acc = 0.f;
#pragma unroll
    for (int ky = 0; ky < 3; ++ky)
#pragma unroll
        for (int kx = 0; kx < 3; ++kx) {
            int py = y + 1 - ky, px = xx + 1 - kx;
            if (py >= 0 && py < HH && px >= 0 && px < WW)
                acc += outacc[((size_t)cb * 576 + c * 9 + ky * 3 + kx) * HW + py * WW + px];
        }
    size_t o = ((size_t)b * CC + c) * HW + p;
    out[o] = x[o] + 0.25f * acc;
}

extern "C" void kernel_launch(void* const* d_in, const int* in_sizes, int n_in,
                              void* d_out, int out_size, void* d_ws, size_t ws_size,
                              hipStream_t stream) {
    const float* x       = (const float*)d_in[0];
    const float* w_base  = (const float*)d_in[1];
    const float* b_base  = (const float*)d_in[2];
    const float* a_base  = (const float*)d_in[3];
    const float* w_match = (const float*)d_in[4];
    const float* b_match = (const float*)d_in[5];
    const float* a_match = (const float*)d_in[6];
    const float* w_asm   = (const float*)d_in[7];
    const float* b_asm   = (const float*)d_in[8];
    const float* a_asm   = (const float*)d_in[9];
    float* out = (float*)d_out;

    // ---- pick chunk size CB by workspace ----
    const size_t fixed = ((size_t)BB * C2 * HW * 4) * 2 + ((size_t)BB * CC * HW * 2) +
                         ((size_t)BB * HW * 4) * 3 + ((size_t)BB * NTOT * 4) +
                         ((size_t)9 * NTOT * 4) + 65536;
    const size_t perCB = ((size_t)HW * KC * 2 * 2) + ((size_t)NPAD2 * KC * 2 * 2) +
                         ((size_t)HW * NPAD2 * 2) + ((size_t)HW * NT26 * 4) +
                         ((size_t)HW * 4) + ((size_t)576 * NPAD2 * 2) +
                         ((size_t)576 * HW * 4) + 65536;
    int CB = 32;
    while (CB > 1 && fixed + perCB * CB > ws_size) CB >>= 1;

    char* ws = (char*)d_ws;
    size_t off = 0;
    auto alloc_b = [&](size_t bytes) {
        void* p = (void*)(ws + off);
        off += bytes;
        off = (off + 255) & ~(size_t)255;
        return p;
    };
    float*  mb      = (float*)alloc_b((size_t)BB * C2 * HW * 4);
    float*  rm_full = (float*)alloc_b((size_t)BB * C2 * HW * 4);
    __bf16* base_f  = (__bf16*)alloc_b((size_t)BB * CC * HW * 2);
    float*  mbss    = (float*)alloc_b((size_t)BB * HW * 4);
    float*  rmss    = (float*)alloc_b((size_t)BB * HW * 4);
    float*  qub     = (float*)alloc_b((size_t)BB * HW * 4);
    float*  sinv    = (float*)alloc_b((size_t)BB * NTOT * 4);
    int*    nbr_pos = (int*)alloc_b((size_t)9 * NTOT * 4);
    __bf16* xpat_h  = (__bf16*)alloc_b((size_t)CB * HW * KC * 2);
    __bf16* xpat_l  = (__bf16*)alloc_b((size_t)CB * HW * KC * 2);
    __bf16* wib_h   = (__bf16*)alloc_b((size_t)CB * NPAD2 * KC * 2);
    __bf16* wib_l   = (__bf16*)alloc_b((size_t)CB * NPAD2 * KC * 2);
    __bf16* tbuf    = (__bf16*)alloc_b((size_t)CB * HW * NPAD2 * 2);
    float*  partS   = (float*)alloc_b((size_t)CB * HW * NT26 * 4);
    float*  fin     = (float*)alloc_b((size_t)CB * HW * 4);
    __bf16* Vb      = (__bf16*)alloc_b((size_t)CB * 576 * NPAD2 * 2);
    float*  outacc  = (float*)alloc_b((size_t)CB * 576 * HW * 4);
    if (off > ws_size) return;

    k_feats<<<dim3(BB * HW / 256, 8), 256, 0, stream>>>(
        x, w_base, b_base, a_base, w_match, b_match, a_match, w_asm, b_asm, a_asm,
        mb, rm_full, base_f);
    k_ss<<<BB * HW / 256, 256, 0, stream>>>(mb, rm_full, mbss, rmss);
    k_nbr<<<(NTOT + 255) / 256, 256, 0, stream>>>(nbr_pos);
    k_qnorm<<<BB * HW / 256, 256, 0, stream>>>(mbss, qub);
    k_norms<<<(BB * NTOT + 255) / 256, 256, 0, stream>>>(rmss, nbr_pos, sinv);

    for (int b0 = 0; b0 < BB; b0 += CB) {
        k_xpat<<<dim3(HW * KC / 256, CB), 256, 0, stream>>>(mb, xpat_h, xpat_l, b0);
        k_wib<<<dim3(NPAD2 * KC / 256, CB), 256, 0, stream>>>(rm_full, nbr_pos, wib_h, wib_l, b0);
        k_corr_mfma<<<dim3(16, NT26, CB), 256, 0, stream>>>(
            xpat_h, xpat_l, wib_h, wib_l, sinv, qub, tbuf, partS, b0);
        k_rowsum<<<CB * HW / 256, 256, 0, stream>>>(partS, fin);
        k_vgather<<<dim3(NPAD2 / 256, 576, CB), 256, 0, stream>>>(base_f, nbr_pos, Vb, b0);
        k_fold_mfma<<<dim3(8, 9, CB), 256, 0, stream>>>(Vb, tbuf, fin, outacc);
        k_epilogue<<<CB * CC * HW / 256, 256, 0, stream>>>(x, outacc, out, b0);
    }
}

// Round 7
// 908.071 us; speedup vs baseline: 1.2193x; 1.2193x over previous
//
#include <hip/hip_runtime.h>
#include <hip/hip_bf16.h>
#include <math.h>

#define BB 32
#define CC 64
#define C2 32
#define HH 32
#define WW 32
#define HW 1024
#define NTOT 3278
#define NPAD2 3328   // padded N (multiple of 128) for MFMA corr + fold
#define NT26 26      // NPAD2 / 128
#define KC 288       // correlation K = C2*9

typedef __bf16 bf16x8 __attribute__((ext_vector_type(8)));
typedef float  f32x4  __attribute__((ext_vector_type(4)));

__device__ __constant__ int SC_SIZE[5] = {32, 28, 25, 22, 19};
__device__ __constant__ int SC_OFF[6]  = {0, 1024, 1808, 2433, 2917, 3278};

// ---------------- fused feature kernel: LDS-staged, x read once ----------------
// block = 64 pixels; 4 waves = 4 out-channel groups of 32:
//   og0: mb (w_base) + mbss; og1: rm_full (w_match) + rmss; og2/3: base (w_asm) bf16
#define XS_STR 65
#define WS_STR 132
__global__ void __launch_bounds__(256, 1) k_feats(
        const float* __restrict__ x,
        const float* __restrict__ wb, const float* __restrict__ bb, const float* __restrict__ ab,
        const float* __restrict__ wm, const float* __restrict__ bm, const float* __restrict__ am,
        const float* __restrict__ wa, const float* __restrict__ ba, const float* __restrict__ aa,
        float* __restrict__ mb, float* __restrict__ rmf, __bf16* __restrict__ basef,
        float* __restrict__ mbss, float* __restrict__ rmss) {
    __shared__ float Xs[64 * XS_STR];     // [c][p]
    __shared__ float Wls[64 * WS_STR];    // [c][o]  o: 0-31 mb, 32-63 rm, 64-127 base
    __shared__ float bsh[128];
    __shared__ float ash3[3];
    int tid = threadIdx.x;
    int g0 = blockIdx.x * 64;             // first global pixel of tile (64-aligned, within one image)
    int b = g0 >> 10, p0 = g0 & 1023;

    // stage x tile: row c = 64 consecutive floats (coalesced)
    const float* xb = x + (size_t)b * CC * HW + p0;
    for (int i = tid; i < 64 * 64; i += 256) {
        int c = i >> 6, p = i & 63;
        Xs[c * XS_STR + p] = xb[(size_t)c * HW + p];
    }
    // stage weights transposed [c][o]
    for (int i = tid; i < 128 * 64; i += 256) {
        int o = i >> 6, c = i & 63;
        float w = (o < 32) ? wb[o * CC + c] : (o < 64) ? wm[(o - 32) * CC + c] : wa[(o - 64) * CC + c];
        Wls[c * WS_STR + o] = w;
    }
    if (tid < 128) bsh[tid] = (tid < 32) ? bb[tid] : (tid < 64) ? bm[tid - 32] : ba[tid - 64];
    if (tid == 128) ash3[0] = ab[0];
    if (tid == 129) ash3[1] = am[0];
    if (tid == 130) ash3[2] = aa[0];
    __syncthreads();

    int p = tid & 63, og = tid >> 6;
    int o0 = og * 32;
    float acc[32];
#pragma unroll
    for (int oi = 0; oi < 32; ++oi) acc[oi] = bsh[o0 + oi];
    for (int c = 0; c < 64; ++c) {
        float xv = Xs[c * XS_STR + p];
        const float* wr = &Wls[c * WS_STR + o0];
#pragma unroll
        for (int oi = 0; oi < 32; ++oi) acc[oi] += wr[oi] * xv;
    }
    int pp = p0 + p;
    if (og == 0) {
        float alpha = ash3[0], ss = 0.f;
#pragma unroll
        for (int oi = 0; oi < 32; ++oi) {
            float v = acc[oi] >= 0.f ? acc[oi] : alpha * acc[oi];
            mb[((size_t)b * C2 + oi) * HW + pp] = v;
            ss += v * v;
        }
        mbss[(size_t)b * HW + pp] = ss;
    } else if (og == 1) {
        float alpha = ash3[1], ss = 0.f;
#pragma unroll
        for (int oi = 0; oi < 32; ++oi) {
            float v = acc[oi] >= 0.f ? acc[oi] : alpha * acc[oi];
            rmf[((size_t)b * C2 + oi) * HW + pp] = v;
            ss += v * v;
        }
        rmss[(size_t)b * HW + pp] = ss;
    } else {
        float alpha = ash3[2];
        int ob = o0 - 64;
#pragma unroll
        for (int oi = 0; oi < 32; ++oi) {
            float v = acc[oi] >= 0.f ? acc[oi] : alpha * acc[oi];
            basef[((size_t)b * CC + ob + oi) * HW + pp] = (__bf16)v;
        }
    }
}

// ---------------- neighbor table: full-grid position of tap kk at concat-index n, or -1 ----------------
__global__ void k_nbr(int* __restrict__ nbr_pos) {
    int n = blockIdx.x * blockDim.x + threadIdx.x;
    if (n >= NTOT) return;
    int s = 0;
    while (s < 4 && n >= SC_OFF[s + 1]) ++s;
    int q = n - SC_OFF[s];
    int hs = SC_SIZE[s];
    int ny = q / hs, nx = q % hs;
    for (int dy = 0; dy < 3; ++dy)
        for (int dx = 0; dx < 3; ++dx) {
            int yy = ny + dy - 1, xx = nx + dx - 1;
            int pos = -1;
            if (yy >= 0 && yy < hs && xx >= 0 && xx < hs)
                pos = ((yy * HH) / hs) * WW + (xx * WW) / hs;
            nbr_pos[(dy * 3 + dx) * NTOT + n] = pos;
        }
}

// ---------------- per-(b,p) logit upper bound: Mub = 10*||xp[p]|| from mbss 9-tap ----------------
__global__ void k_qnorm(const float* __restrict__ mbss, float* __restrict__ qub) {
    int t = blockIdx.x * blockDim.x + threadIdx.x;   // [0, BB*HW)
    int b = t >> 10, p = t & 1023;
    int y = p >> 5, x = p & 31;
    float s = 0.f;
#pragma unroll
    for (int dy = 0; dy < 3; ++dy)
#pragma unroll
        for (int dx = 0; dx < 3; ++dx) {
            int yy = y + dy - 1, xx = x + dx - 1;
            if (yy >= 0 && yy < HH && xx >= 0 && xx < WW)
                s += mbss[(size_t)b * HW + yy * WW + xx];
        }
    qub[t] = 10.0f * sqrtf(s);
}

// ---------------- per-(b,n) filter norms from rmss 9-tap; sinv = 10/max(norm,1e-4) ----------------
__global__ void k_norms(const float* __restrict__ rmss, const int* __restrict__ nbr_pos,
                        float* __restrict__ sinv) {
    int t = blockIdx.x * blockDim.x + threadIdx.x;
    if (t >= BB * NTOT) return;
    int b = t / NTOT, n = t % NTOT;
    float sum = 0.f;
#pragma unroll
    for (int kk = 0; kk < 9; ++kk) {
        int pos = nbr_pos[kk * NTOT + n];
        if (pos >= 0) sum += rmss[(size_t)b * HW + pos];
    }
    sinv[t] = 10.0f / fmaxf(sqrtf(sum), 1e-4f);
}

// ---------------- xpat gather: mb patches -> [cb][p][KC] bf16 hi/lo ----------------
__global__ void k_xpat(const float* __restrict__ mb, __bf16* __restrict__ xh,
                       __bf16* __restrict__ xl, int b0) {
    int t = blockIdx.x * 256 + threadIdx.x;   // over HW*KC
    int cb = blockIdx.y;
    int p = t / KC, k = t % KC;
    int c2 = k / 9, kk = k % 9;
    int py = (p >> 5) + kk / 3 - 1;
    int px = (p & 31) + kk % 3 - 1;
    float v = 0.f;
    if (py >= 0 && py < HH && px >= 0 && px < WW)
        v = mb[((size_t)(b0 + cb) * C2 + c2) * HW + py * WW + px];
    __bf16 hi = (__bf16)v;
    size_t o = ((size_t)cb * HW + p) * KC + k;
    xh[o] = hi;
    xl[o] = (__bf16)(v - (float)hi);
}

// ---------------- wib gather: wi rows from rm_full -> [cb][n][KC] bf16 hi/lo ----------------
__global__ void k_wib(const float* __restrict__ rmf, const int* __restrict__ nbr_pos,
                      __bf16* __restrict__ wh, __bf16* __restrict__ wl, int b0) {
    int t = blockIdx.x * 256 + threadIdx.x;   // over NPAD2*KC
    int cb = blockIdx.y;
    int n = t / KC, k = t % KC;
    int c2 = k / 9, kk = k % 9;
    float v = 0.f;
    if (n < NTOT) {
        int pos = nbr_pos[kk * NTOT + n];
        if (pos >= 0) v = rmf[((size_t)(b0 + cb) * C2 + c2) * HW + pos];
    }
    __bf16 hi = (__bf16)v;
    size_t o = ((size_t)cb * NPAD2 + n) * KC + k;
    wh[o] = hi;
    wl[o] = (__bf16)(v - (float)hi);
}

// ---------------- correlation GEMM (MFMA, split-bf16) + t = exp(v - Mub[p]) epilogue ----------------
__global__ void k_corr_mfma(const __bf16* __restrict__ xh, const __bf16* __restrict__ xl,
                            const __bf16* __restrict__ wh, const __bf16* __restrict__ wl,
                            const float* __restrict__ sinv, const float* __restrict__ qub,
                            __bf16* __restrict__ tbuf, float* __restrict__ partS, int b0) {
    int ptile = blockIdx.x;   // 16 tiles of 64 p
    int ntile = blockIdx.y;   // 26 tiles of 128 n
    int cb    = blockIdx.z;
    int tid  = threadIdx.x;
    int lane = tid & 63, wave = tid >> 6;
    int row16 = lane & 15, quad = lane >> 4;

    __shared__ __bf16 Ah[64 * 40], Al[64 * 40];
    __shared__ __bf16 Bh[128 * 40], Bl[128 * 40];
    __shared__ float sMub[64];
    __shared__ float redS[4][64];

    if (tid < 64) sMub[tid] = qub[(size_t)(b0 + cb) * HW + ptile * 64 + tid];

    const __bf16* Aph = xh + ((size_t)cb * HW + ptile * 64) * KC;
    const __bf16* Apl = xl + ((size_t)cb * HW + ptile * 64) * KC;
    const __bf16* Bph = wh + ((size_t)cb * NPAD2 + ntile * 128) * KC;
    const __bf16* Bpl = wl + ((size_t)cb * NPAD2 + ntile * 128) * KC;

    f32x4 acc[4][2];
#pragma unroll
    for (int i = 0; i < 4; ++i)
#pragma unroll
        for (int j = 0; j < 2; ++j) acc[i][j] = (f32x4){0.f, 0.f, 0.f, 0.f};

    int lr = tid >> 2, lk = (tid & 3) * 8;
    for (int k0 = 0; k0 < KC; k0 += 32) {
        *(bf16x8*)&Ah[lr * 40 + lk] = *(const bf16x8*)(Aph + (size_t)lr * KC + k0 + lk);
        *(bf16x8*)&Al[lr * 40 + lk] = *(const bf16x8*)(Apl + (size_t)lr * KC + k0 + lk);
#pragma unroll
        for (int i = 0; i < 2; ++i) {
            int r = tid + i * 256;
            int rr = r >> 2, rk = (r & 3) * 8;
            *(bf16x8*)&Bh[rr * 40 + rk] = *(const bf16x8*)(Bph + (size_t)rr * KC + k0 + rk);
            *(bf16x8*)&Bl[rr * 40 + rk] = *(const bf16x8*)(Bpl + (size_t)rr * KC + k0 + rk);
        }
        __syncthreads();
        bf16x8 ah[4], al[4], bh[2], bl[2];
#pragma unroll
        for (int m = 0; m < 4; ++m) {
            ah[m] = *(const bf16x8*)&Ah[(m * 16 + row16) * 40 + quad * 8];
            al[m] = *(const bf16x8*)&Al[(m * 16 + row16) * 40 + quad * 8];
        }
#pragma unroll
        for (int nb = 0; nb < 2; ++nb) {
            bh[nb] = *(const bf16x8*)&Bh[(wave * 32 + nb * 16 + row16) * 40 + quad * 8];
            bl[nb] = *(const bf16x8*)&Bl[(wave * 32 + nb * 16 + row16) * 40 + quad * 8];
        }
#pragma unroll
        for (int m = 0; m < 4; ++m)
#pragma unroll
            for (int nb = 0; nb < 2; ++nb) {
                acc[m][nb] = __builtin_amdgcn_mfma_f32_16x16x32_bf16(ah[m], bh[nb], acc[m][nb], 0, 0, 0);
                acc[m][nb] = __builtin_amdgcn_mfma_f32_16x16x32_bf16(ah[m], bl[nb], acc[m][nb], 0, 0, 0);
                acc[m][nb] = __builtin_amdgcn_mfma_f32_16x16x32_bf16(al[m], bh[nb], acc[m][nb], 0, 0, 0);
            }
        __syncthreads();
    }

    // ---- epilogue: v = acc*sinv[n]; t = exp(v - Mub[p]); row-partial sums ----
    int nn[2];
    float sv[2];
    bool valid[2];
#pragma unroll
    for (int nb = 0; nb < 2; ++nb) {
        nn[nb] = ntile * 128 + wave * 32 + nb * 16 + row16;
        valid[nb] = nn[nb] < NTOT;
        sv[nb] = valid[nb] ? sinv[(size_t)(b0 + cb) * NTOT + nn[nb]] : 0.f;
    }
    float sm[4][4] = {};
#pragma unroll
    for (int m = 0; m < 4; ++m)
#pragma unroll
        for (int nb = 0; nb < 2; ++nb) {
            size_t rb = ((size_t)cb * HW + ptile * 64 + m * 16) * NPAD2 + nn[nb];
#pragma unroll
            for (int r = 0; r < 4; ++r) {
                float mub = sMub[m * 16 + quad * 4 + r];
                float e = valid[nb] ? __expf(acc[m][nb][r] * sv[nb] - mub) : 0.f;
                tbuf[rb + (size_t)(quad * 4 + r) * NPAD2] = (__bf16)e;
                sm[m][r] += e;
            }
        }
#pragma unroll
    for (int msk = 1; msk < 16; msk <<= 1)
#pragma unroll
        for (int m = 0; m < 4; ++m)
#pragma unroll
            for (int r = 0; r < 4; ++r) sm[m][r] += __shfl_xor(sm[m][r], msk, 64);
    if (row16 == 0)
#pragma unroll
        for (int m = 0; m < 4; ++m)
#pragma unroll
            for (int r = 0; r < 4; ++r) redS[wave][m * 16 + quad * 4 + r] = sm[m][r];
    __syncthreads();
    if (wave == 0 && row16 == 0) {
#pragma unroll
        for (int m = 0; m < 4; ++m)
#pragma unroll
            for (int r = 0; r < 4; ++r) {
                int p = m * 16 + quad * 4 + r;
                float S = redS[0][p] + redS[1][p] + redS[2][p] + redS[3][p];
                partS[((size_t)cb * HW + ptile * 64 + p) * NT26 + ntile] = S;
            }
    }
}

// ---------------- row sum reduce: fin[row] = 1 / sum_nt partS ----------------
__global__ void k_rowsum(const float* __restrict__ partS, float* __restrict__ fin) {
    int row = blockIdx.x * 256 + threadIdx.x;   // [0, CB*HW)
    float s = 0.f;
#pragma unroll
    for (int nt = 0; nt < NT26; ++nt) s += partS[(size_t)row * NT26 + nt];
    fin[row] = 1.0f / fmaxf(s, 1e-38f);
}

// ---------------- V gather: Vb[cb][m=576][NPAD2] bf16 from base_full ----------------
__global__ void k_vgather(const __bf16* __restrict__ basef, const int* __restrict__ nbr_pos,
                          __bf16* __restrict__ Vb, int b0) {
    int n = blockIdx.x * 256 + threadIdx.x;
    int m = blockIdx.y;
    int cb = blockIdx.z;
    int c = m / 9, kk = m % 9;
    __bf16 v = (__bf16)0.f;
    if (n < NTOT) {
        int pos = nbr_pos[kk * NTOT + n];
        if (pos >= 0) v = basef[((size_t)(b0 + cb) * CC + c) * HW + pos];
    }
    Vb[((size_t)cb * 576 + m) * NPAD2 + n] = v;
}

// ---------------- fold GEMM (MFMA bf16, K-step 64, reg prefetch) ----------------
// outacc[cb][m][p] = (1/S[p]) * sum_n V[m,n]*t[p,n]
#define FSTR 72   // LDS row stride in bf16 (144 B, 16B-aligned)
__global__ void k_fold_mfma(const __bf16* __restrict__ Vb, const __bf16* __restrict__ tbuf,
                            const float* __restrict__ fin, float* __restrict__ outacc) {
    int ptile = blockIdx.x;   // 8 tiles of 128 p
    int mtile = blockIdx.y;   // 9 tiles of 64 m
    int cb    = blockIdx.z;
    int tid  = threadIdx.x;
    int lane = tid & 63, wave = tid >> 6;
    int row16 = lane & 15, quad = lane >> 4;

    __shared__ __bf16 Als[64 * FSTR];
    __shared__ __bf16 Bls[128 * FSTR];

    const __bf16* Vp = Vb   + (size_t)cb * 576 * NPAD2 + (size_t)mtile * 64 * NPAD2;
    const __bf16* Pp = tbuf + (size_t)cb * HW  * NPAD2 + (size_t)ptile * 128 * NPAD2;

    f32x4 acc[4][2];
#pragma unroll
    for (int i = 0; i < 4; ++i)
#pragma unroll
        for (int j = 0; j < 2; ++j) acc[i][j] = (f32x4){0.f, 0.f, 0.f, 0.f};

    int sr = tid >> 3, sk = (tid & 7) * 8;   // staging: 32 rows/pass, 64 k
    bf16x8 pa[2], pb[4];
#pragma unroll
    for (int i = 0; i < 2; ++i)
        pa[i] = *(const bf16x8*)(Vp + (size_t)(i * 32 + sr) * NPAD2 + sk);
#pragma unroll
    for (int i = 0; i < 4; ++i)
        pb[i] = *(const bf16x8*)(Pp + (size_t)(i * 32 + sr) * NPAD2 + sk);

    for (int k0 = 0; k0 < NPAD2; k0 += 64) {
        __syncthreads();   // previous step's LDS reads done
#pragma unroll
        for (int i = 0; i < 2; ++i)
            *(bf16x8*)&Als[(i * 32 + sr) * FSTR + sk] = pa[i];
#pragma unroll
        for (int i = 0; i < 4; ++i)
            *(bf16x8*)&Bls[(i * 32 + sr) * FSTR + sk] = pb[i];
        // prefetch next step while MFMA runs
        if (k0 + 64 < NPAD2) {
#pragma unroll
            for (int i = 0; i < 2; ++i)
                pa[i] = *(const bf16x8*)(Vp + (size_t)(i * 32 + sr) * NPAD2 + k0 + 64 + sk);
#pragma unroll
            for (int i = 0; i < 4; ++i)
                pb[i] = *(const bf16x8*)(Pp + (size_t)(i * 32 + sr) * NPAD2 + k0 + 64 + sk);
        }
        __syncthreads();   // LDS tile ready
#pragma unroll
        for (int kh = 0; kh < 2; ++kh) {
            bf16x8 af[4], bf[2];
#pragma unroll
            for (int mb = 0; mb < 4; ++mb)
                af[mb] = *(const bf16x8*)&Als[(mb * 16 + row16) * FSTR + kh * 32 + quad * 8];
#pragma unroll
            for (int pbi = 0; pbi < 2; ++pbi)
                bf[pbi] = *(const bf16x8*)&Bls[(wave * 32 + pbi * 16 + row16) * FSTR + kh * 32 + quad * 8];
#pragma unroll
            for (int mb = 0; mb < 4; ++mb)
#pragma unroll
                for (int pbi = 0; pbi < 2; ++pbi)
                    acc[mb][pbi] = __builtin_amdgcn_mfma_f32_16x16x32_bf16(af[mb], bf[pbi], acc[mb][pbi], 0, 0, 0);
        }
    }
    float fsc[2];
#pragma unroll
    for (int pbi = 0; pbi < 2; ++pbi)
        fsc[pbi] = fin[(size_t)cb * HW + ptile * 128 + wave * 32 + pbi * 16 + row16];
#pragma unroll
    for (int mb = 0; mb < 4; ++mb)
#pragma unroll
        for (int pbi = 0; pbi < 2; ++pbi) {
#pragma unroll
            for (int r = 0; r < 4; ++r) {
                int mg = mtile * 64 + mb * 16 + quad * 4 + r;
                int pg = ptile * 128 + wave * 32 + pbi * 16 + row16;
                outacc[((size_t)cb * 576 + mg) * HW + pg] = acc[mb][pbi][r] * fsc[pbi];
            }
        }
}

// ---------------- epilogue ----------------
__global__ void k_epilogue(const float* __restrict__ x, const float* __restrict__ outacc,
                           float* __restrict__ out, int b0) {
    int t = blockIdx.x * blockDim.x + threadIdx.x;
    int cb = t >> 16;
    int c = (t >> 10) & 63;
    int p = t & 1023;
    int b = b0 + cb;
    int y = p >> 5, xx = p & 31;
    float acc = 0.f;
#pragma unroll
    for (int ky = 0; ky < 3; ++ky)
#pragma unroll
        for (int kx = 0; kx < 3; ++kx) {
            int py = y + 1 - ky, px = xx + 1 - kx;
            if (py >= 0 && py < HH && px >= 0 && px < WW)
                acc += outacc[((size_t)cb * 576 + c * 9 + ky * 3 + kx) * HW + py * WW + px];
        }
    size_t o = ((size_t)b * CC + c) * HW + p;
    out[o] = x[o] + 0.25f * acc;
}

extern "C" void kernel_launch(void* const* d_in, const int* in_sizes, int n_in,
                              void* d_out, int out_size, void* d_ws, size_t ws_size,
                              hipStream_t stream) {
    const float* x       = (const float*)d_in[0];
    const float* w_base  = (const float*)d_in[1];
    const float* b_base  = (const float*)d_in[2];
    const float* a_base  = (const float*)d_in[3];
    const float* w_match = (const float*)d_in[4];
    const float* b_match = (const float*)d_in[5];
    const float* a_match = (const float*)d_in[6];
    const float* w_asm   = (const float*)d_in[7];
    const float* b_asm   = (const float*)d_in[8];
    const float* a_asm   = (const float*)d_in[9];
    float* out = (float*)d_out;

    // ---- pick chunk size CB by workspace ----
    const size_t fixed = ((size_t)BB * C2 * HW * 4) * 2 + ((size_t)BB * CC * HW * 2) +
                         ((size_t)BB * HW * 4) * 3 + ((size_t)BB * NTOT * 4) +
                         ((size_t)9 * NTOT * 4) + 65536;
    const size_t perCB = ((size_t)HW * KC * 2 * 2) + ((size_t)NPAD2 * KC * 2 * 2) +
                         ((size_t)HW * NPAD2 * 2) + ((size_t)HW * NT26 * 4) +
                         ((size_t)HW * 4) + ((size_t)576 * NPAD2 * 2) +
                         ((size_t)576 * HW * 4) + 65536;
    int CB = 32;
    while (CB > 1 && fixed + perCB * CB > ws_size) CB >>= 1;

    char* ws = (char*)d_ws;
    size_t off = 0;
    auto alloc_b = [&](size_t bytes) {
        void* p = (void*)(ws + off);
        off += bytes;
        off = (off + 255) & ~(size_t)255;
        return p;
    };
    float*  mb      = (float*)alloc_b((size_t)BB * C2 * HW * 4);
    float*  rm_full = (float*)alloc_b((size_t)BB * C2 * HW * 4);
    __bf16* base_f  = (__bf16*)alloc_b((size_t)BB * CC * HW * 2);
    float*  mbss    = (float*)alloc_b((size_t)BB * HW * 4);
    float*  rmss    = (float*)alloc_b((size_t)BB * HW * 4);
    float*  qub     = (float*)alloc_b((size_t)BB * HW * 4);
    float*  sinv    = (float*)alloc_b((size_t)BB * NTOT * 4);
    int*    nbr_pos = (int*)alloc_b((size_t)9 * NTOT * 4);
    __bf16* xpat_h  = (__bf16*)alloc_b((size_t)CB * HW * KC * 2);
    __bf16* xpat_l  = (__bf16*)alloc_b((size_t)CB * HW * KC * 2);
    __bf16* wib_h   = (__bf16*)alloc_b((size_t)CB * NPAD2 * KC * 2);
    __bf16* wib_l   = (__bf16*)alloc_b((size_t)CB * NPAD2 * KC * 2);
    __bf16* tbuf    = (__bf16*)alloc_b((size_t)CB * HW * NPAD2 * 2);
    float*  partS   = (float*)alloc_b((size_t)CB * HW * NT26 * 4);
    float*  fin     = (float*)alloc_b((size_t)CB * HW * 4);
    __bf16* Vb      = (__bf16*)alloc_b((size_t)CB * 576 * NPAD2 * 2);
    float*  outacc  = (float*)alloc_b((size_t)CB * 576 * HW * 4);
    if (off > ws_size) return;

    k_feats<<<BB * HW / 64, 256, 0, stream>>>(
        x, w_base, b_base, a_base, w_match, b_match, a_match, w_asm, b_asm, a_asm,
        mb, rm_full, base_f, mbss, rmss);
    k_nbr<<<(NTOT + 255) / 256, 256, 0, stream>>>(nbr_pos);
    k_qnorm<<<BB * HW / 256, 256, 0, stream>>>(mbss, qub);
    k_norms<<<(BB * NTOT + 255) / 256, 256, 0, stream>>>(rmss, nbr_pos, sinv);

    for (int b0 = 0; b0 < BB; b0 += CB) {
        k_xpat<<<dim3(HW * KC / 256, CB), 256, 0, stream>>>(mb, xpat_h, xpat_l, b0);
        k_wib<<<dim3(NPAD2 * KC / 256, CB), 256, 0, stream>>>(rm_full, nbr_pos, wib_h, wib_l, b0);
        k_corr_mfma<<<dim3(16, NT26, CB), 256, 0, stream>>>(
            xpat_h, xpat_l, wib_h, wib_l, sinv, qub, tbuf, partS, b0);
        k_rowsum<<<CB * HW / 256, 256, 0, stream>>>(partS, fin);
        k_vgather<<<dim3(NPAD2 / 256, 576, CB), 256, 0, stream>>>(base_f, nbr_pos, Vb, b0);
        k_fold_mfma<<<dim3(8, 9, CB), 256, 0, stream>>>(Vb, tbuf, fin, outacc);
        k_epilogue<<<CB * CC * HW / 256, 256, 0, stream>>>(x, outacc, out, b0);
    }
}